// Round 4
// baseline (8392.333 us; speedup 1.0000x reference)
//
#include <hip/hip_runtime.h>
#include <hip/hip_fp16.h>

// Problem dims
#define BB   128
#define TT   512
#define INS  64
#define HH   512
#define K0   576    // INS + HH (layer0 fused [x | h1] GEMM depth)
#define K1   1024   // HH + HH  (layer1 fused [h1 | h2] GEMM depth)
#define PAD0 584    // LDS pad (16B-aligned rows)
#define PAD1 1032
#define H2   256
#define FS   16     // flag stride in ints (64B apart -> no store-line contention)
#define RING 4      // h ring depth

typedef _Float16 f16;
typedef f16 f16x4 __attribute__((ext_vector_type(4)));
typedef f16 f16x8 __attribute__((ext_vector_type(8)));
typedef float f32x4 __attribute__((ext_vector_type(4)));

__device__ __forceinline__ float sigmoidf_(float x) {
  return 1.0f / (1.0f + __expf(-x));
}
__device__ __forceinline__ float tanhf_(float x) {
  return 1.0f - 2.0f / (__expf(2.0f * x) + 1.0f);
}

// LLC-coherent h access (bypass non-coherent per-XCD L2): relaxed agent atomics.
__device__ __forceinline__ f16x8 ldg_h(const f16* p) {
  union { unsigned long long q[2]; f16x8 v; } u;
  const unsigned long long* qp = (const unsigned long long*)p;
  u.q[0] = __hip_atomic_load(qp,     __ATOMIC_RELAXED, __HIP_MEMORY_SCOPE_AGENT);
  u.q[1] = __hip_atomic_load(qp + 1, __ATOMIC_RELAXED, __HIP_MEMORY_SCOPE_AGENT);
  return u.v;
}
__device__ __forceinline__ void stg_h(f16* p, unsigned int pk) {
  __hip_atomic_store((unsigned int*)p, pk, __ATOMIC_RELAXED, __HIP_MEMORY_SCOPE_AGENT);
}
__device__ __forceinline__ int ldf(const int* p) {
  return __hip_atomic_load(p, __ATOMIC_RELAXED, __HIP_MEMORY_SCOPE_AGENT);
}

// Persistent dataflow 2-layer LSTM. NO grid barrier: producer epoch flags.
// Grid: 256 WGs x 256 thr (4 waves). wg<128 -> layer0, else layer1.
// WG (mg 0..1, ng 0..63) owns M-rows mg*64..+64, h-cols ng*8..+8 (32 gate rows).
// Wave w handles rows wrow=mg*64+w*16. Flags: one per wave (256/layer/mg-half).
// flags1[i]=s+1 <=> that L0 wave finished step s (h1_s stored at LLC).
// flags2[i]=s   <=> that L1 wave finished superstep s (h2_{s-1} stored).
// L0 step s:  wait all f1>=s (h1_{s-1} ready) && all f2>=s-3 (ring anti-dep).
// L1 sstep s: wait all f1>=s && all f2>=s-1 (h2_{s-2} ready). s=1..512.
// Ring depth 4 > max skew (2) + 1 -> no WAR races (derivation in round log).
__global__ __launch_bounds__(256, 1) void lstm_persist(
    const float* __restrict__ x,
    const float* __restrict__ Wih0, const float* __restrict__ Whh0,
    const float* __restrict__ bih0, const float* __restrict__ bhh0,
    const float* __restrict__ Wih1, const float* __restrict__ Whh1,
    const float* __restrict__ bih1, const float* __restrict__ bhh1,
    int* __restrict__ flags, f16* __restrict__ h1ring, f16* __restrict__ h2ring)
{
  extern __shared__ f16 Ws[];   // [32][PAD0 or PAD1] (layer-dependent)

  const int tid  = threadIdx.x;
  const int wg   = blockIdx.x;
  const bool isL1 = (wg >= 128);
  const int w2   = wg & 127;
  const int mg   = w2 >> 6;
  const int ng   = w2 & 63;
  const int wid  = tid >> 6;
  const int lane = tid & 63;

  // ---- stage my layer's weights -> LDS (fp16) ----
  // LDS row r = q*8+j -> gate row g = q*512 + ng*8 + j (q: 0=i,1=f,2=g,3=o)
  if (!isL1) {
    for (int e4 = tid; e4 < 32 * (K0 / 4); e4 += 256) {
      int r = e4 / (K0 / 4), k = (e4 - r * (K0 / 4)) * 4;
      int g = ((r >> 3) << 9) + (ng << 3) + (r & 7);
      float4 v = (k < INS)
          ? *reinterpret_cast<const float4*>(Wih0 + g * INS + k)
          : *reinterpret_cast<const float4*>(Whh0 + g * HH + (k - INS));
      f16x4 h; h[0]=(f16)v.x; h[1]=(f16)v.y; h[2]=(f16)v.z; h[3]=(f16)v.w;
      *reinterpret_cast<f16x4*>(&Ws[r * PAD0 + k]) = h;
    }
  } else {
    for (int e4 = tid; e4 < 32 * (K1 / 4); e4 += 256) {
      int r = e4 >> 8, k = (e4 & 255) * 4;
      int g = ((r >> 3) << 9) + (ng << 3) + (r & 7);
      float4 v = (k < HH)
          ? *reinterpret_cast<const float4*>(Wih1 + g * HH + k)
          : *reinterpret_cast<const float4*>(Whh1 + g * HH + (k - HH));
      f16x4 h; h[0]=(f16)v.x; h[1]=(f16)v.y; h[2]=(f16)v.z; h[3]=(f16)v.w;
      *reinterpret_cast<f16x4*>(&Ws[r * PAD1 + k]) = h;
    }
  }

  const int  wrow = mg * 64 + wid * 16;
  const int  row  = wrow + (lane & 15);
  const int  col0 = lane & 15;
  const int  kq   = (lane >> 4) * 8;
  const int  hcol = (ng << 3) + (lane & 7);
  const int  rowb = wrow + ((lane >> 4) << 2);
  const bool low  = (lane & 8) == 0;
  const bool evn  = (lane & 1) == 0;

  float bias[2];
  #pragma unroll
  for (int n = 0; n < 2; n++) {
    int c = n * 16 + col0;
    int g = ((c >> 3) << 9) + (ng << 3) + (c & 7);
    bias[n] = isL1 ? (bih1[g] + bhh1[g]) : (bih0[g] + bhh0[g]);
  }
  __syncthreads();   // weights staged (only sync in the kernel)

  int* f1 = flags + (mg)     * 256 * FS;   // layer0 flags, my half
  int* f2 = flags + (2 + mg) * 256 * FS;   // layer1 flags, my half
  int* myflag = (isL1 ? f2 : f1) + (ng * 4 + wid) * FS;

  f32x4 cst = {};  // cell state (same value maintained in low/high partner lanes)

  if (!isL1) {
    // ================= LAYER 0: steps 0..511 =================
    for (int s = 0; s < TT; ++s) {
      const f16* h1r = h1ring + ((s + RING - 1) & (RING - 1)) * (BB * HH);
      f16*       h1w = h1ring + (s & (RING - 1)) * (BB * HH);

      // issue x loads early (independent of h)
      const float* xb = x + ((size_t)row * TT + (size_t)s) * INS;
      float4 xq0 = *reinterpret_cast<const float4*>(xb + kq);
      float4 xq1 = *reinterpret_cast<const float4*>(xb + kq + 4);
      float4 xq2 = *reinterpret_cast<const float4*>(xb + 32 + kq);
      float4 xq3 = *reinterpret_cast<const float4*>(xb + 32 + kq + 4);

      // poll: all f1 >= s, all f2 >= s-3 (ring anti-dep)
      int spin = 0;
      for (;;) {
        int m1 = ldf(f1 + (4 * lane + 0) * FS);
        m1 = min(m1, ldf(f1 + (4 * lane + 1) * FS));
        m1 = min(m1, ldf(f1 + (4 * lane + 2) * FS));
        m1 = min(m1, ldf(f1 + (4 * lane + 3) * FS));
        int m2 = ldf(f2 + (4 * lane + 0) * FS);
        m2 = min(m2, ldf(f2 + (4 * lane + 1) * FS));
        m2 = min(m2, ldf(f2 + (4 * lane + 2) * FS));
        m2 = min(m2, ldf(f2 + (4 * lane + 3) * FS));
        if (__all((m1 >= s) && (m2 >= s - 3))) break;
        if (++spin > (1 << 16)) break;   // safety bailout (never in normal runs)
        __builtin_amdgcn_s_sleep(2);
      }
      asm volatile("" ::: "memory");

      // issue ALL h loads up-front (one LLC latency)
      f16x8 a[16];
      #pragma unroll
      for (int u = 0; u < 16; ++u)
        a[u] = ldg_h(h1r + row * HH + u * 32 + kq);

      // x part (data arrived during poll)
      f16x8 ax0, ax1;
      ax0[0]=(f16)xq0.x; ax0[1]=(f16)xq0.y; ax0[2]=(f16)xq0.z; ax0[3]=(f16)xq0.w;
      ax0[4]=(f16)xq1.x; ax0[5]=(f16)xq1.y; ax0[6]=(f16)xq1.z; ax0[7]=(f16)xq1.w;
      ax1[0]=(f16)xq2.x; ax1[1]=(f16)xq2.y; ax1[2]=(f16)xq2.z; ax1[3]=(f16)xq2.w;
      ax1[4]=(f16)xq3.x; ax1[5]=(f16)xq3.y; ax1[6]=(f16)xq3.z; ax1[7]=(f16)xq3.w;
      f32x4 acc0 = {}, acc1 = {};
      {
        f16x8 b;
        b = *reinterpret_cast<const f16x8*>(&Ws[col0 * PAD0 + kq]);
        acc0 = __builtin_amdgcn_mfma_f32_16x16x32_f16(ax0, b, acc0, 0, 0, 0);
        b = *reinterpret_cast<const f16x8*>(&Ws[(16 + col0) * PAD0 + kq]);
        acc1 = __builtin_amdgcn_mfma_f32_16x16x32_f16(ax0, b, acc1, 0, 0, 0);
        b = *reinterpret_cast<const f16x8*>(&Ws[col0 * PAD0 + 32 + kq]);
        acc0 = __builtin_amdgcn_mfma_f32_16x16x32_f16(ax1, b, acc0, 0, 0, 0);
        b = *reinterpret_cast<const f16x8*>(&Ws[(16 + col0) * PAD0 + 32 + kq]);
        acc1 = __builtin_amdgcn_mfma_f32_16x16x32_f16(ax1, b, acc1, 0, 0, 0);
      }
      #pragma unroll
      for (int u = 0; u < 16; ++u) {
        const int kk = INS + u * 32 + kq;
        f16x8 b0 = *reinterpret_cast<const f16x8*>(&Ws[col0 * PAD0 + kk]);
        f16x8 b1 = *reinterpret_cast<const f16x8*>(&Ws[(16 + col0) * PAD0 + kk]);
        acc0 = __builtin_amdgcn_mfma_f32_16x16x32_f16(a[u], b0, acc0, 0, 0, 0);
        acc1 = __builtin_amdgcn_mfma_f32_16x16x32_f16(a[u], b1, acc1, 0, 0, 0);
      }

      // LSTM cell (frag0 = [i|f], frag1 = [g|o]); identical in partner lanes
      float res[4];
      #pragma unroll
      for (int j = 0; j < 4; j++) {
        float v0 = acc0[j] + bias[0];
        float v1 = acc1[j] + bias[1];
        float p0 = __shfl_xor(v0, 8, 64);
        float p1 = __shfl_xor(v1, 8, 64);
        float ip = low ? v0 : p0;
        float fp = low ? p0 : v0;
        float gp = low ? v1 : p1;
        float op = low ? p1 : v1;
        float cn = sigmoidf_(fp) * cst[j] + sigmoidf_(ip) * tanhf_(gp);
        cst[j] = cn;
        res[j] = sigmoidf_(op) * tanhf_(cn);
      }
      #pragma unroll
      for (int j = 0; j < 4; j++) {
        float other = __shfl_xor(res[j], 1, 64);
        if (low && evn) {
          f16 lo_ = (f16)res[j], hi_ = (f16)other;
          unsigned int pk =
              (unsigned int)__builtin_bit_cast(unsigned short, lo_) |
              ((unsigned int)__builtin_bit_cast(unsigned short, hi_) << 16);
          stg_h(h1w + (rowb + j) * HH + hcol, pk);
        }
      }
      asm volatile("s_waitcnt vmcnt(0)" ::: "memory");  // h at LLC
      if (lane == 0)
        __hip_atomic_store(myflag, s + 1, __ATOMIC_RELAXED, __HIP_MEMORY_SCOPE_AGENT);
    }
  } else {
    // ================= LAYER 1: supersteps 1..512 (computes h2_{s-1}) =====
    for (int s = 1; s <= TT; ++s) {
      const f16* h1r = h1ring + ((s + RING - 1) & (RING - 1)) * (BB * HH);
      const f16* h2r = h2ring + ((s + RING - 2) & (RING - 1)) * (BB * HH);
      f16*       h2w = h2ring + ((s + RING - 1) & (RING - 1)) * (BB * HH);

      // poll: all f1 >= s (h1_{s-1}), all f2 >= s-1 (h2_{s-2})
      int spin = 0;
      for (;;) {
        int m1 = ldf(f1 + (4 * lane + 0) * FS);
        m1 = min(m1, ldf(f1 + (4 * lane + 1) * FS));
        m1 = min(m1, ldf(f1 + (4 * lane + 2) * FS));
        m1 = min(m1, ldf(f1 + (4 * lane + 3) * FS));
        int m2 = ldf(f2 + (4 * lane + 0) * FS);
        m2 = min(m2, ldf(f2 + (4 * lane + 1) * FS));
        m2 = min(m2, ldf(f2 + (4 * lane + 2) * FS));
        m2 = min(m2, ldf(f2 + (4 * lane + 3) * FS));
        if (__all((m1 >= s) && (m2 >= s - 1))) break;
        if (++spin > (1 << 16)) break;
        __builtin_amdgcn_s_sleep(2);
      }
      asm volatile("" ::: "memory");

      // issue ALL 32 h loads up-front
      f16x8 a[32];
      #pragma unroll
      for (int u = 0; u < 16; ++u)
        a[u] = ldg_h(h1r + row * HH + u * 32 + kq);
      #pragma unroll
      for (int u = 0; u < 16; ++u)
        a[16 + u] = ldg_h(h2r + row * HH + u * 32 + kq);

      f32x4 acc0 = {}, acc1 = {};
      #pragma unroll
      for (int u = 0; u < 32; ++u) {
        const int kk = u * 32 + kq;
        f16x8 b0 = *reinterpret_cast<const f16x8*>(&Ws[col0 * PAD1 + kk]);
        f16x8 b1 = *reinterpret_cast<const f16x8*>(&Ws[(16 + col0) * PAD1 + kk]);
        acc0 = __builtin_amdgcn_mfma_f32_16x16x32_f16(a[u], b0, acc0, 0, 0, 0);
        acc1 = __builtin_amdgcn_mfma_f32_16x16x32_f16(a[u], b1, acc1, 0, 0, 0);
      }

      float res[4];
      #pragma unroll
      for (int j = 0; j < 4; j++) {
        float v0 = acc0[j] + bias[0];
        float v1 = acc1[j] + bias[1];
        float p0 = __shfl_xor(v0, 8, 64);
        float p1 = __shfl_xor(v1, 8, 64);
        float ip = low ? v0 : p0;
        float fp = low ? p0 : v0;
        float gp = low ? v1 : p1;
        float op = low ? p1 : v1;
        float cn = sigmoidf_(fp) * cst[j] + sigmoidf_(ip) * tanhf_(gp);
        cst[j] = cn;
        res[j] = sigmoidf_(op) * tanhf_(cn);
      }
      #pragma unroll
      for (int j = 0; j < 4; j++) {
        float other = __shfl_xor(res[j], 1, 64);
        if (low && evn) {
          f16 lo_ = (f16)res[j], hi_ = (f16)other;
          unsigned int pk =
              (unsigned int)__builtin_bit_cast(unsigned short, lo_) |
              ((unsigned int)__builtin_bit_cast(unsigned short, hi_) << 16);
          stg_h(h2w + (rowb + j) * HH + hcol, pk);
        }
      }
      asm volatile("s_waitcnt vmcnt(0)" ::: "memory");
      if (lane == 0)
        __hip_atomic_store(myflag, s, __ATOMIC_RELAXED, __HIP_MEMORY_SCOPE_AGENT);
    }
  }
}

__global__ void fc1_kernel(const f16* __restrict__ last, const float* __restrict__ w,
                           const float* __restrict__ b, float* __restrict__ z) {
  const int bb = blockIdx.x;   // batch row
  const int j  = threadIdx.x;  // 0..255 output col
  const f16*   lp = last + bb * HH;
  const float* wp = w + j * HH;
  float s = b[j];
  #pragma unroll 8
  for (int k = 0; k < HH; k++) s += (float)lp[k] * wp[k];
  z[bb * H2 + j] = fmaxf(s, 0.0f);
}

__global__ void fc2_kernel(const float* __restrict__ z, const float* __restrict__ w,
                           const float* __restrict__ b, float* __restrict__ out) {
  const int bb = threadIdx.x;  // 0..127
  float s = b[0];
  #pragma unroll 8
  for (int k = 0; k < H2; k++) s += z[bb * H2 + k] * w[k];
  out[bb] = s;
}

extern "C" void kernel_launch(void* const* d_in, const int* in_sizes, int n_in,
                              void* d_out, int out_size, void* d_ws, size_t ws_size,
                              hipStream_t stream) {
  const float* x     = (const float*)d_in[0];
  const float* Wih0  = (const float*)d_in[1];
  const float* Whh0  = (const float*)d_in[2];
  const float* bih0  = (const float*)d_in[3];
  const float* bhh0  = (const float*)d_in[4];
  const float* Wih1  = (const float*)d_in[5];
  const float* Whh1  = (const float*)d_in[6];
  const float* bih1  = (const float*)d_in[7];
  const float* bhh1  = (const float*)d_in[8];
  const float* fc1w  = (const float*)d_in[9];
  const float* fc1b  = (const float*)d_in[10];
  const float* fc2w  = (const float*)d_in[11];
  const float* fc2b  = (const float*)d_in[12];

  char* ws = (char*)d_ws;
  int*  flags = (int*)ws;                                 // 4*256*FS ints = 64KB
  const size_t FLAGS_B = (size_t)4 * 256 * FS * sizeof(int);
  f16*  h1 = (f16*)(ws + FLAGS_B);                        // RING x B x H
  f16*  h2 = h1 + (size_t)RING * BB * HH;                 // RING x B x H
  float* z = (float*)(ws + FLAGS_B + (size_t)2 * RING * BB * HH * sizeof(f16));

  // zero flags + rings each replay (h_{-1}=h_{-2}=0, epochs=0)
  hipMemsetAsync(ws, 0, FLAGS_B + (size_t)2 * RING * BB * HH * sizeof(f16), stream);

  const size_t smem = (size_t)32 * PAD1 * sizeof(f16);   // 64.5KB (max of layers)
  lstm_persist<<<256, 256, smem, stream>>>(x, Wih0, Whh0, bih0, bhh0,
                                           Wih1, Whh1, bih1, bhh1, flags, h1, h2);

  const f16* last = h2 + ((TT - 1) & (RING - 1)) * (BB * HH);  // h2_{511}, slot 3
  fc1_kernel<<<BB, 256, 0, stream>>>(last, fc1w, fc1b, z);
  fc2_kernel<<<1, BB, 0, stream>>>(z, fc2w, fc2b, (float*)d_out);
}